// Round 16
// baseline (817.193 us; speedup 1.0000x reference)
//
#include <hip/hip_runtime.h>
#include <math.h>

// ---------------------------------------------------------------------------
// GTAN2 R16: R15 (746us best) + w1 hoisted out of k_hop's critical chain.
// k_w1: edge-parallel exp(lrelu(x1[s]+h1[t])) -> w1s[e] (coalesced s_sorted/
// t_sorted; 800K-thread TLP hides the h1a scatter). k_hop phase 1 staging is
// now two coalesced loads (ts, w1s) -- no per-lane scatter, no exp in chain.
// All else byte-identical to R15 (BM=32 k_hop, grid 1563).
// ---------------------------------------------------------------------------

typedef __attribute__((ext_vector_type(8))) short short8;
typedef __attribute__((ext_vector_type(4))) float f32x4;
#define MFMA16 __builtin_amdgcn_mfma_f32_16x16x32_bf16

__device__ __forceinline__ float lrelu02(float v) { return v > 0.f ? v : 0.2f * v; }

__device__ __forceinline__ float2 bf2f2(unsigned int v) {
    return make_float2(__uint_as_float(v << 16), __uint_as_float(v & 0xffff0000u));
}
__device__ __forceinline__ unsigned int f2bf(float f) {  // RNE bf16
    unsigned int u = __float_as_uint(f);
    u += 0x7fffu + ((u >> 16) & 1u);
    return u >> 16;
}
__device__ __forceinline__ float hi_part(float f) {
    return __uint_as_float(__float_as_uint(f) & 0xffff0000u);
}
__device__ __forceinline__ uint4 pack_hi(const float4& a, const float4& b) {
    uint4 r;
    r.x = (__float_as_uint(a.x) >> 16) | (__float_as_uint(a.y) & 0xffff0000u);
    r.y = (__float_as_uint(a.z) >> 16) | (__float_as_uint(a.w) & 0xffff0000u);
    r.z = (__float_as_uint(b.x) >> 16) | (__float_as_uint(b.y) & 0xffff0000u);
    r.w = (__float_as_uint(b.z) >> 16) | (__float_as_uint(b.w) & 0xffff0000u);
    return r;
}
__device__ __forceinline__ uint4 pack_lo(const float4& a, const float4& b) {
    uint4 r;
    r.x = f2bf(a.x - hi_part(a.x)) | (f2bf(a.y - hi_part(a.y)) << 16);
    r.y = f2bf(a.z - hi_part(a.z)) | (f2bf(a.w - hi_part(a.w)) << 16);
    r.z = f2bf(b.x - hi_part(b.x)) | (f2bf(b.y - hi_part(b.y)) << 16);
    r.w = f2bf(b.z - hi_part(b.z)) | (f2bf(b.w - hi_part(b.w)) << 16);
    return r;
}

// ---------------- CSR build ----------------
__global__ __launch_bounds__(256) void k_count(const int* __restrict__ s, int* __restrict__ cnt, int E) {
    int e = blockIdx.x * 256 + threadIdx.x;
    if (e < E) atomicAdd(&cnt[s[e]], 1);
}

__global__ __launch_bounds__(256) void k_scan1(const int* __restrict__ cnt, int* __restrict__ bs, int N) {
    __shared__ int sh[256];
    int idx = blockIdx.x * 256 + threadIdx.x;
    sh[threadIdx.x] = (idx < N) ? cnt[idx] : 0;
    __syncthreads();
#pragma unroll
    for (int off = 128; off; off >>= 1) {
        if (threadIdx.x < off) sh[threadIdx.x] += sh[threadIdx.x + off];
        __syncthreads();
    }
    if (threadIdx.x == 0) bs[blockIdx.x] = sh[0];
}

__global__ __launch_bounds__(256) void k_scan2(int* __restrict__ bs, int G) {
    __shared__ int sh[256];
    int t = threadIdx.x;
    int v = (t < G) ? bs[t] : 0;
    sh[t] = v;
    __syncthreads();
    int val = v;
#pragma unroll
    for (int off = 1; off < 256; off <<= 1) {
        int o = (t >= off) ? sh[t - off] : 0;
        __syncthreads();
        val += o; sh[t] = val;
        __syncthreads();
    }
    if (t < G) bs[t] = val - v;  // exclusive
}

__global__ __launch_bounds__(256) void k_scan3(const int* __restrict__ cnt, const int* __restrict__ bs,
                                               int* __restrict__ rp, int N) {
    __shared__ int sh[256];
    int t = threadIdx.x;
    int idx = blockIdx.x * 256 + t;
    int v = (idx < N) ? cnt[idx] : 0;
    sh[t] = v;
    __syncthreads();
    int val = v;
#pragma unroll
    for (int off = 1; off < 256; off <<= 1) {
        int o = (t >= off) ? sh[t - off] : 0;
        __syncthreads();
        val += o; sh[t] = val;
        __syncthreads();
    }
    if (idx <= N) rp[idx] = val - v + bs[blockIdx.x];
}

__global__ __launch_bounds__(256) void k_scatter(const int* __restrict__ s, const int* __restrict__ t,
                                                 const int* __restrict__ rp, int* __restrict__ cursor,
                                                 int* __restrict__ t_sorted, int* __restrict__ s_sorted, int E) {
    int e = blockIdx.x * 256 + threadIdx.x;
    if (e < E) {
        int u = s[e];
        int pos = atomicAdd(&cursor[u], 1);
        int idx = rp[u] + pos;
        t_sorted[idx] = t[e];
        s_sorted[idx] = u;
    }
}

// ---------------- W split ----------------
__global__ __launch_bounds__(256) void k_wsplit(const float* __restrict__ W,
                                                unsigned short* __restrict__ Whi,
                                                unsigned short* __restrict__ Wlo, int total) {
    int i = blockIdx.x * 256 + threadIdx.x;
    if (i < total) {
        float f = W[i];
        unsigned int u = __float_as_uint(f);
        Whi[i] = (unsigned short)(u >> 16);
        Wlo[i] = (unsigned short)f2bf(f - __uint_as_float(u & 0xffff0000u));
    }
}

// ---------------- k_prep: V vectors (W^T a1, W^T a2) + constants ------------
__global__ __launch_bounds__(256) void k_prep(
    const float* __restrict__ fcsW, const float* __restrict__ fcsb,
    const float* __restrict__ a1, const float* __restrict__ a2,
    float* __restrict__ Vf, unsigned short* __restrict__ Vh,
    unsigned short* __restrict__ Vl, float* __restrict__ cvec) {
    int i = blockIdx.x;
    int t = threadIdx.x;
    const float* W = fcsW + (size_t)i * 16384;
    if (t < 128) {
        float s1 = 0.f, s2 = 0.f;
        for (int j = 0; j < 128; ++j) {
            float w = W[j * 128 + t];
            s1 = fmaf(w, a1[i * 128 + j], s1);
            s2 = fmaf(w, a2[i * 128 + j], s2);
        }
        Vf[i * 128 + t] = s1;
        Vf[(16 + i) * 128 + t] = s2;
        Vh[i * 128 + t] = (unsigned short)(__float_as_uint(s1) >> 16);
        Vl[i * 128 + t] = (unsigned short)f2bf(s1 - hi_part(s1));
        Vh[(16 + i) * 128 + t] = (unsigned short)(__float_as_uint(s2) >> 16);
        Vl[(16 + i) * 128 + t] = (unsigned short)f2bf(s2 - hi_part(s2));
    } else if (t == 128) {
        float c1 = 0.f, c2 = 0.f;
        for (int j = 0; j < 128; ++j) {
            c1 = fmaf(fcsb[i * 128 + j], a1[i * 128 + j], c1);
            c2 = fmaf(fcsb[i * 128 + j], a2[i * 128 + j], c2);
        }
        cvec[i] = c1;
        cvec[16 + i] = c2;
    }
}

// ---------------- fc1: 3-term, BM=64, staged dense stores ----------------
__global__ __launch_bounds__(256) void k_fc1(
    const float* __restrict__ Xf,
    const unsigned short* __restrict__ Wh, const unsigned short* __restrict__ Wl,
    const float* __restrict__ bias,
    unsigned short* __restrict__ Yhi, unsigned short* __restrict__ Ylo, int N) {
    __shared__ unsigned short Shi[64 * 128];
    __shared__ unsigned short Slo[64 * 128];
    const int tid = threadIdx.x;
    const int r0 = blockIdx.x * 64;
    const int lane = tid & 63;
    const int w = tid >> 6;
    const int wr = (w >> 1) * 32, wc = (w & 1) * 64;
    const int frow = lane & 15;
    const int fk = lane >> 4;
    const int q4 = lane >> 4;

    f32x4 acc[2][4];
#pragma unroll
    for (int i = 0; i < 2; ++i)
#pragma unroll
        for (int j = 0; j < 4; ++j) acc[i][j] = (f32x4){0.f, 0.f, 0.f, 0.f};

    const float4 z4 = make_float4(0.f, 0.f, 0.f, 0.f);
#pragma unroll
    for (int kc = 0; kc < 8; ++kc) {
        short8 ah[2], al[2];
#pragma unroll
        for (int ri = 0; ri < 2; ++ri) {
            int row = r0 + wr + ri * 16 + frow;
            float4 va = z4, vb = z4;
            if (row < N) {
                const float* p = Xf + (size_t)row * 256 + kc * 32 + fk * 8;
                va = *(const float4*)p;
                vb = *(const float4*)(p + 4);
            }
            uint4 h = pack_hi(va, vb);
            uint4 l = pack_lo(va, vb);
            ah[ri] = *(short8*)&h;
            al[ri] = *(short8*)&l;
        }
#pragma unroll
        for (int ci = 0; ci < 4; ++ci) {
            int col = wc + ci * 16 + frow;
            short8 bh = *(const short8*)(Wh + (size_t)col * 256 + kc * 32 + fk * 8);
            short8 bl = *(const short8*)(Wl + (size_t)col * 256 + kc * 32 + fk * 8);
#pragma unroll
            for (int ri = 0; ri < 2; ++ri) {
                acc[ri][ci] = MFMA16(ah[ri], bh, acc[ri][ci], 0, 0, 0);
                acc[ri][ci] = MFMA16(ah[ri], bl, acc[ri][ci], 0, 0, 0);
                acc[ri][ci] = MFMA16(al[ri], bh, acc[ri][ci], 0, 0, 0);
            }
        }
    }

#pragma unroll
    for (int ci = 0; ci < 4; ++ci) {
        int col = wc + ci * 16 + frow;
        float bcol = bias[col];
#pragma unroll
        for (int ri = 0; ri < 2; ++ri) {
            f32x4 v = acc[ri][ci];
#pragma unroll
            for (int reg = 0; reg < 4; ++reg) {
                float val = fmaxf(v[reg] + bcol, 0.f);
                int row = wr + ri * 16 + q4 * 4 + reg;
                int dw = (col >> 1) ^ ((row & 12) << 1);
                Shi[row * 128 + dw * 2 + (col & 1)] = (unsigned short)(__float_as_uint(val) >> 16);
                Slo[row * 128 + dw * 2 + (col & 1)] = (unsigned short)f2bf(val - hi_part(val));
            }
        }
    }
    __syncthreads();
#pragma unroll
    for (int q = 0; q < 4; ++q) {
        int idx = q * 256 + tid;
        int row = idx >> 4;
        int gc = idx & 15;
        int dwb = (gc * 4) ^ ((row & 12) << 1);
        int grow = r0 + row;
        if (grow < N) {
            *(uint4*)(Yhi + (size_t)grow * 128 + gc * 8) = *(const uint4*)(Shi + row * 128 + dwb * 2);
            *(uint4*)(Ylo + (size_t)grow * 128 + gc * 8) = *(const uint4*)(Slo + row * 128 + dwb * 2);
        }
    }
}

// ---------------- k_xdots: x1a/xa2a for ALL hops in one N x 32 GEMM ---------
__global__ __launch_bounds__(256) void k_xdots(
    const unsigned short* __restrict__ Xhi, const unsigned short* __restrict__ Xlo,
    const unsigned short* __restrict__ Vh, const unsigned short* __restrict__ Vl,
    const float* __restrict__ cvec,
    float* __restrict__ x1a_all, float* __restrict__ xa2a_all, int N) {
    const int tid = threadIdx.x;
    const int r0 = blockIdx.x * 64;
    const int lane = tid & 63;
    const int w = tid >> 6;
    const int wr = w * 16;
    const int frow = lane & 15;
    const int fk = lane >> 4;
    const int q4 = lane >> 4;

    f32x4 acc[2];
    acc[0] = (f32x4){0.f, 0.f, 0.f, 0.f};
    acc[1] = (f32x4){0.f, 0.f, 0.f, 0.f};

    const short8 z8 = (short8){0, 0, 0, 0, 0, 0, 0, 0};
#pragma unroll
    for (int kc = 0; kc < 4; ++kc) {
        int row = r0 + wr + frow;
        bool ok = row < N;
        short8 ah = ok ? *(const short8*)(Xhi + (size_t)row * 128 + kc * 32 + fk * 8) : z8;
        short8 al = ok ? *(const short8*)(Xlo + (size_t)row * 128 + kc * 32 + fk * 8) : z8;
#pragma unroll
        for (int ci = 0; ci < 2; ++ci) {
            int col = ci * 16 + frow;
            short8 bh = *(const short8*)(Vh + (size_t)col * 128 + kc * 32 + fk * 8);
            short8 bl = *(const short8*)(Vl + (size_t)col * 128 + kc * 32 + fk * 8);
            acc[ci] = MFMA16(ah, bh, acc[ci], 0, 0, 0);
            acc[ci] = MFMA16(ah, bl, acc[ci], 0, 0, 0);
            acc[ci] = MFMA16(al, bh, acc[ci], 0, 0, 0);
        }
    }

#pragma unroll
    for (int ci = 0; ci < 2; ++ci) {
        int col = ci * 16 + frow;
        float c = cvec[col];
#pragma unroll
        for (int reg = 0; reg < 4; ++reg) {
            int grow = r0 + wr + q4 * 4 + reg;
            if (grow < N) {
                float val = acc[ci][reg] + c;
                if (col < 10) x1a_all[(size_t)col * N + grow] = val;
                else if (col >= 16 && col < 26) xa2a_all[(size_t)(col - 16) * N + grow] = val;
            }
        }
    }
}

// ---------------- k_w1: edge-parallel attention weights ----------------
__global__ __launch_bounds__(256) void k_w1(
    const float* __restrict__ x1a, const float* __restrict__ h1in,
    const int* __restrict__ ss, const int* __restrict__ ts,
    float* __restrict__ w1s, int E) {
    int e = blockIdx.x * 256 + threadIdx.x;
    if (e < E) w1s[e] = expf(lrelu02(x1a[ss[e]] + h1in[ts[e]]));
}

// ---------------- k_hop: fused gather + GEMM, BM=32, w1 precomputed ---------
__global__ __launch_bounds__(256) void k_hop(
    const unsigned short* __restrict__ table, const unsigned short* __restrict__ xh,
    const float* __restrict__ x1a, const float* __restrict__ xa2a,
    const float* __restrict__ w1s,
    const int* __restrict__ rp, const int* __restrict__ ts,
    const unsigned short* __restrict__ Wh, const unsigned short* __restrict__ Wl,
    const float* __restrict__ bias, const float* __restrict__ vnext,
    const float* __restrict__ cnextp,
    unsigned short* __restrict__ Hout, float* __restrict__ h1out, int N) {
    __shared__ unsigned short gS[32 * 128];  // 8 KB: g tile, then C-stage
    __shared__ uint2 ew[4][64];
    __shared__ float dotbuf[32][2];
    const int tid = threadIdx.x;
    const int wid = tid >> 6;
    const int lane = tid & 63;
    const int r0 = blockIdx.x * 32;

    // ---- phase 1: each wave gathers 8 rows; staging = 2 coalesced loads ----
    for (int j = 0; j < 8; ++j) {
        int gr = wid * 8 + j;
        int u = r0 + gr;
        unsigned int packed = 0u;
        if (u < N) {
            float x1u = x1a[u];
            float w2 = expf(lrelu02(x1u + xa2a[u]));
            float2 xr = bf2f2(*(const unsigned int*)(xh + (size_t)u * 128 + lane * 2));
            float accx = w2 * xr.x, accy = w2 * xr.y;
            float div = w2;
            int p0 = rp[u], p1 = rp[u + 1];
            for (int base = p0; base < p1; base += 64) {
                int e = base + lane;
                uint2 pk = make_uint2(0u, 0u);
                if (e < p1) {
                    pk.x = (unsigned int)ts[e];
                    pk.y = ((const unsigned int*)w1s)[e];
                }
                ew[wid][lane] = pk;
                int m = p1 - base; if (m > 64) m = 64;
                int m8 = (m + 7) & ~7;
                for (int jj = 0; jj < m8; jj += 8) {
                    uint2 q[8];
#pragma unroll
                    for (int k = 0; k < 8; ++k) q[k] = ew[wid][jj + k];
                    unsigned int hv[8];
#pragma unroll
                    for (int k = 0; k < 8; ++k)
                        hv[k] = *(const unsigned int*)(table + (size_t)q[k].x * 128 + lane * 2);
#pragma unroll
                    for (int k = 0; k < 8; ++k) {
                        float ww = __uint_as_float(q[k].y);
                        float2 f = bf2f2(hv[k]);
                        accx = fmaf(ww, f.x, accx);
                        accy = fmaf(ww, f.y, accy);
                        div += ww;
                    }
                }
            }
            float ox = accx / div, oy = accy / div;
            packed = f2bf(ox) | (f2bf(oy) << 16);
        }
        int dw = (((lane >> 2) ^ (gr & 7)) << 2) | (lane & 3);
        *((unsigned int*)gS + gr * 64 + dw) = packed;
    }
    __syncthreads();

    // ---- phase 2: GEMM (wave = 16 rows x 64 cols) ----
    const int w = wid;
    const int wr = (w >> 1) * 16, wc = (w & 1) * 64;
    const int frow = lane & 15;
    const int fk = lane >> 4;
    const int q4 = lane >> 4;
    const bool dodot = vnext != nullptr;

    f32x4 acc[4];
#pragma unroll
    for (int j = 0; j < 4; ++j) acc[j] = (f32x4){0.f, 0.f, 0.f, 0.f};

#pragma unroll
    for (int kc = 0; kc < 4; ++kc) {
        int row = wr + frow;
        int gg = kc * 4 + fk;
        short8 ah = *(const short8*)(gS + row * 128 + ((gg ^ (row & 7)) * 8));
#pragma unroll
        for (int ci = 0; ci < 4; ++ci) {
            int col = wc + ci * 16 + frow;
            short8 bh = *(const short8*)(Wh + (size_t)col * 128 + kc * 32 + fk * 8);
            short8 bl = *(const short8*)(Wl + (size_t)col * 128 + kc * 32 + fk * 8);
            acc[ci] = MFMA16(ah, bh, acc[ci], 0, 0, 0);
            acc[ci] = MFMA16(ah, bl, acc[ci], 0, 0, 0);
        }
    }
    __syncthreads();  // all A-frag reads done; gS becomes C-stage

    float dotA[4] = {};
#pragma unroll
    for (int ci = 0; ci < 4; ++ci) {
        int col = wc + ci * 16 + frow;
        float bcol = bias[col];
        float vc = dodot ? vnext[col] : 0.f;
        f32x4 v = acc[ci];
#pragma unroll
        for (int reg = 0; reg < 4; ++reg) {
            float val = v[reg] + bcol;
            val = val > 0.f ? val : expf(val) - 1.f;  // elu
            int row = wr + q4 * 4 + reg;
            int dw = (col >> 1) ^ ((row & 12) << 1);
            gS[row * 128 + dw * 2 + (col & 1)] = (unsigned short)f2bf(val);
            dotA[reg] = fmaf(val, vc, dotA[reg]);
        }
    }
#pragma unroll
    for (int m = 1; m < 16; m <<= 1)
#pragma unroll
        for (int reg = 0; reg < 4; ++reg)
            dotA[reg] += __shfl_xor(dotA[reg], m, 64);
    if (frow == 0) {
#pragma unroll
        for (int reg = 0; reg < 4; ++reg) {
            int rl = wr + q4 * 4 + reg;
            dotbuf[rl][w & 1] = dotA[reg];
        }
    }
    __syncthreads();

#pragma unroll
    for (int q = 0; q < 2; ++q) {
        int idx = q * 256 + tid;        // 0..511
        int row = idx >> 4;             // 0..31
        int gc = idx & 15;
        int dwb = (gc * 4) ^ ((row & 12) << 1);
        uint4 vv = *(const uint4*)(gS + row * 128 + dwb * 2);
        int grow = r0 + row;
        if (grow < N) *(uint4*)(Hout + (size_t)grow * 128 + gc * 8) = vv;
    }
    if (dodot && tid < 32) {
        int grow = r0 + tid;
        if (grow < N) h1out[grow] = dotbuf[tid][0] + dotbuf[tid][1] + cnextp[0];
    }
}

// ---------------- fc2: barrier-free, zero-LDS, 2-term, BM=64 ----------------
__global__ __launch_bounds__(256) void k_fc2(
    const unsigned short* __restrict__ Xhi,
    const unsigned short* __restrict__ Wh, const unsigned short* __restrict__ Wl,
    const float* __restrict__ bias, float* __restrict__ Yf, int N) {
    const int tid = threadIdx.x;
    const int r0 = blockIdx.x * 64;
    const int lane = tid & 63;
    const int w = tid >> 6;
    const int wr = w * 16;
    const int frow = lane & 15;
    const int fk = lane >> 4;
    const int q4 = lane >> 4;

    f32x4 acc[4];
#pragma unroll
    for (int j = 0; j < 4; ++j) acc[j] = (f32x4){0.f, 0.f, 0.f, 0.f};

    const short8 z8 = (short8){0, 0, 0, 0, 0, 0, 0, 0};
#pragma unroll
    for (int kc = 0; kc < 4; ++kc) {
        int row = r0 + wr + frow;
        short8 ah = (row < N) ? *(const short8*)(Xhi + (size_t)row * 128 + kc * 32 + fk * 8) : z8;
#pragma unroll
        for (int ci = 0; ci < 4; ++ci) {
            int col = ci * 16 + frow;
            short8 bh = *(const short8*)(Wh + (size_t)col * 128 + kc * 32 + fk * 8);
            short8 bl = *(const short8*)(Wl + (size_t)col * 128 + kc * 32 + fk * 8);
            acc[ci] = MFMA16(ah, bh, acc[ci], 0, 0, 0);
            acc[ci] = MFMA16(ah, bl, acc[ci], 0, 0, 0);
        }
    }

#pragma unroll
    for (int ci = 0; ci < 4; ++ci) {
        int col = ci * 16 + frow;
        float bcol = bias[col];
#pragma unroll
        for (int reg = 0; reg < 4; ++reg) {
            int grow = r0 + wr + q4 * 4 + reg;
            if (grow < N) Yf[(size_t)grow * 64 + col] = acc[ci][reg] + bcol;
        }
    }
}

// ---------------- launch ----------------
extern "C" void kernel_launch(void* const* d_in, const int* in_sizes, int n_in,
                              void* d_out, int out_size, void* d_ws, size_t ws_size,
                              hipStream_t stream) {
    const float* x_in = (const float*)d_in[0];
    const int*   s    = (const int*)d_in[1];
    const int*   t    = (const int*)d_in[2];
    const float* fc1W = (const float*)d_in[3];
    const float* fc1b = (const float*)d_in[4];
    const float* fcsW = (const float*)d_in[5];
    const float* fcsb = (const float*)d_in[6];
    const float* a1   = (const float*)d_in[7];
    const float* a2   = (const float*)d_in[8];
    const float* fc2W = (const float*)d_in[9];
    const float* fc2b = (const float*)d_in[10];

    const int N = in_sizes[0] / 256;  // 50000
    const int E = in_sizes[1];        // 800000
    const int G = (N + 255) / 256;
    const int NB64 = (N + 63) / 64;   // 782
    const int NB32 = (N + 31) / 32;   // 1563
    const int EB = (E + 255) / 256;   // 3125

    char* ws = (char*)d_ws;
    size_t off = 0;
    auto alloc = [&](size_t bytes) -> void* {
        void* p = ws + off;
        off += (bytes + 255) & ~(size_t)255;
        return p;
    };
    unsigned short* xbuf_hi = (unsigned short*)alloc((size_t)N * 128 * 2);
    unsigned short* xbuf_lo = (unsigned short*)alloc((size_t)N * 128 * 2);
    unsigned short* hA      = (unsigned short*)alloc((size_t)N * 128 * 2);
    unsigned short* hB      = (unsigned short*)alloc((size_t)N * 128 * 2);
    unsigned short* Whi  = (unsigned short*)alloc((size_t)10 * 16384 * 2);
    unsigned short* Wlo  = (unsigned short*)alloc((size_t)10 * 16384 * 2);
    unsigned short* W1hi = (unsigned short*)alloc((size_t)128 * 256 * 2);
    unsigned short* W1lo = (unsigned short*)alloc((size_t)128 * 256 * 2);
    unsigned short* W2hi = (unsigned short*)alloc((size_t)64 * 128 * 2);
    unsigned short* W2lo = (unsigned short*)alloc((size_t)64 * 128 * 2);
    float* Vf   = (float*)alloc((size_t)32 * 128 * 4);
    unsigned short* Vh = (unsigned short*)alloc((size_t)32 * 128 * 2);
    unsigned short* Vl = (unsigned short*)alloc((size_t)32 * 128 * 2);
    float* cvec = (float*)alloc((size_t)32 * 4);
    float* x1a_all  = (float*)alloc((size_t)10 * N * 4);
    float* xa2a_all = (float*)alloc((size_t)10 * N * 4);
    float* h1aA = (float*)alloc((size_t)N * 4);
    float* h1aB = (float*)alloc((size_t)N * 4);
    float* w1s  = (float*)alloc((size_t)E * 4);
    int* row_ptr  = (int*)alloc((size_t)(N + 1) * 4);
    int* cnt      = (int*)alloc((size_t)N * 4);
    int* bsums    = (int*)alloc((size_t)1024);
    int* t_sorted = (int*)alloc((size_t)E * 4);
    int* s_sorted = (int*)alloc((size_t)E * 4);

    // CSR build
    hipMemsetAsync(cnt, 0, (size_t)N * 4, stream);
    k_count<<<EB, 256, 0, stream>>>(s, cnt, E);
    k_scan1<<<G, 256, 0, stream>>>(cnt, bsums, N);
    k_scan2<<<1, 256, 0, stream>>>(bsums, G);
    k_scan3<<<G, 256, 0, stream>>>(cnt, bsums, row_ptr, N);
    hipMemsetAsync(cnt, 0, (size_t)N * 4, stream);
    k_scatter<<<EB, 256, 0, stream>>>(s, t, row_ptr, cnt, t_sorted, s_sorted, E);

    // W splits + V prep
    k_wsplit<<<(10 * 16384 + 255) / 256, 256, 0, stream>>>(fcsW, Whi, Wlo, 10 * 16384);
    k_wsplit<<<(128 * 256 + 255) / 256, 256, 0, stream>>>(fc1W, W1hi, W1lo, 128 * 256);
    k_wsplit<<<(64 * 128 + 255) / 256, 256, 0, stream>>>(fc2W, W2hi, W2lo, 64 * 128);
    hipMemsetAsync(Vf, 0, (size_t)32 * 128 * 4, stream);
    hipMemsetAsync(Vh, 0, (size_t)32 * 128 * 2, stream);
    hipMemsetAsync(Vl, 0, (size_t)32 * 128 * 2, stream);
    hipMemsetAsync(cvec, 0, (size_t)32 * 4, stream);
    k_prep<<<10, 256, 0, stream>>>(fcsW, fcsb, a1, a2, Vf, Vh, Vl, cvec);

    // fc1 + relu -> split planes
    k_fc1<<<NB64, 256, 0, stream>>>(x_in, W1hi, W1lo, fc1b, xbuf_hi, xbuf_lo, N);

    // x-side scalars for all hops
    k_xdots<<<NB64, 256, 0, stream>>>(xbuf_hi, xbuf_lo, Vh, Vl, cvec,
                                      x1a_all, xa2a_all, N);

    // hops: edge-parallel w1 -> fused gather+GEMM, ping-pong h / h1a
    const unsigned short* table = xbuf_hi;
    const float* h1in = xa2a_all;  // hop 0: h1 == xa2 (h == x)
    for (int i = 0; i < 10; ++i) {
        k_w1<<<EB, 256, 0, stream>>>(x1a_all + (size_t)i * N, h1in,
                                     s_sorted, t_sorted, w1s, E);
        unsigned short* hout = (i & 1) ? hB : hA;
        float* h1out = (i & 1) ? h1aB : h1aA;
        const float* vnext = (i < 9) ? (Vf + (size_t)(16 + i + 1) * 128) : nullptr;
        k_hop<<<NB32, 256, 0, stream>>>(table, xbuf_hi,
                                        x1a_all + (size_t)i * N, xa2a_all + (size_t)i * N,
                                        w1s, row_ptr, t_sorted,
                                        Whi + (size_t)i * 16384, Wlo + (size_t)i * 16384,
                                        fcsb + (size_t)i * 128, vnext, cvec + (16 + i + 1),
                                        hout, h1out, N);
        table = hout;
        h1in = h1out;
    }

    // fc2
    k_fc2<<<NB64, 256, 0, stream>>>(table, W2hi, W2lo, fc2b, (float*)d_out, N);
}

// Round 17
// 766.625 us; speedup vs baseline: 1.0660x; 1.0660x over previous
//
#include <hip/hip_runtime.h>
#include <math.h>

// ---------------------------------------------------------------------------
// GTAN2 R17: R15 base (746us best; R16's w1-hoist reverted — it moved work,
// didn't remove it). Two deltas:
//  1) t_sorted stores t*128 (pre-scaled): k_hop gather uses 32-bit unsigned
//     offsets (saddr+voffset form), cutting 64-bit addr VALU in the hot loop.
//  2) fc1 BM=32 (grid 1563) — same occupancy fix that worked for k_hop.
// ---------------------------------------------------------------------------

typedef __attribute__((ext_vector_type(8))) short short8;
typedef __attribute__((ext_vector_type(4))) float f32x4;
#define MFMA16 __builtin_amdgcn_mfma_f32_16x16x32_bf16

__device__ __forceinline__ float lrelu02(float v) { return v > 0.f ? v : 0.2f * v; }

__device__ __forceinline__ float2 bf2f2(unsigned int v) {
    return make_float2(__uint_as_float(v << 16), __uint_as_float(v & 0xffff0000u));
}
__device__ __forceinline__ unsigned int f2bf(float f) {  // RNE bf16
    unsigned int u = __float_as_uint(f);
    u += 0x7fffu + ((u >> 16) & 1u);
    return u >> 16;
}
__device__ __forceinline__ float hi_part(float f) {
    return __uint_as_float(__float_as_uint(f) & 0xffff0000u);
}
__device__ __forceinline__ uint4 pack_hi(const float4& a, const float4& b) {
    uint4 r;
    r.x = (__float_as_uint(a.x) >> 16) | (__float_as_uint(a.y) & 0xffff0000u);
    r.y = (__float_as_uint(a.z) >> 16) | (__float_as_uint(a.w) & 0xffff0000u);
    r.z = (__float_as_uint(b.x) >> 16) | (__float_as_uint(b.y) & 0xffff0000u);
    r.w = (__float_as_uint(b.z) >> 16) | (__float_as_uint(b.w) & 0xffff0000u);
    return r;
}
__device__ __forceinline__ uint4 pack_lo(const float4& a, const float4& b) {
    uint4 r;
    r.x = f2bf(a.x - hi_part(a.x)) | (f2bf(a.y - hi_part(a.y)) << 16);
    r.y = f2bf(a.z - hi_part(a.z)) | (f2bf(a.w - hi_part(a.w)) << 16);
    r.z = f2bf(b.x - hi_part(b.x)) | (f2bf(b.y - hi_part(b.y)) << 16);
    r.w = f2bf(b.z - hi_part(b.z)) | (f2bf(b.w - hi_part(b.w)) << 16);
    return r;
}

// ---------------- CSR build ----------------
__global__ __launch_bounds__(256) void k_count(const int* __restrict__ s, int* __restrict__ cnt, int E) {
    int e = blockIdx.x * 256 + threadIdx.x;
    if (e < E) atomicAdd(&cnt[s[e]], 1);
}

__global__ __launch_bounds__(256) void k_scan1(const int* __restrict__ cnt, int* __restrict__ bs, int N) {
    __shared__ int sh[256];
    int idx = blockIdx.x * 256 + threadIdx.x;
    sh[threadIdx.x] = (idx < N) ? cnt[idx] : 0;
    __syncthreads();
#pragma unroll
    for (int off = 128; off; off >>= 1) {
        if (threadIdx.x < off) sh[threadIdx.x] += sh[threadIdx.x + off];
        __syncthreads();
    }
    if (threadIdx.x == 0) bs[blockIdx.x] = sh[0];
}

__global__ __launch_bounds__(256) void k_scan2(int* __restrict__ bs, int G) {
    __shared__ int sh[256];
    int t = threadIdx.x;
    int v = (t < G) ? bs[t] : 0;
    sh[t] = v;
    __syncthreads();
    int val = v;
#pragma unroll
    for (int off = 1; off < 256; off <<= 1) {
        int o = (t >= off) ? sh[t - off] : 0;
        __syncthreads();
        val += o; sh[t] = val;
        __syncthreads();
    }
    if (t < G) bs[t] = val - v;  // exclusive
}

__global__ __launch_bounds__(256) void k_scan3(const int* __restrict__ cnt, const int* __restrict__ bs,
                                               int* __restrict__ rp, int N) {
    __shared__ int sh[256];
    int t = threadIdx.x;
    int idx = blockIdx.x * 256 + t;
    int v = (idx < N) ? cnt[idx] : 0;
    sh[t] = v;
    __syncthreads();
    int val = v;
#pragma unroll
    for (int off = 1; off < 256; off <<= 1) {
        int o = (t >= off) ? sh[t - off] : 0;
        __syncthreads();
        val += o; sh[t] = val;
        __syncthreads();
    }
    if (idx <= N) rp[idx] = val - v + bs[blockIdx.x];
}

// t_sorted stores t*128 (ushort-element offset of the row) for 32-bit addressing
__global__ __launch_bounds__(256) void k_scatter(const int* __restrict__ s, const int* __restrict__ t,
                                                 const int* __restrict__ rp, int* __restrict__ cursor,
                                                 int* __restrict__ t_sorted, int E) {
    int e = blockIdx.x * 256 + threadIdx.x;
    if (e < E) {
        int u = s[e];
        int pos = atomicAdd(&cursor[u], 1);
        t_sorted[rp[u] + pos] = t[e] << 7;
    }
}

// ---------------- W split ----------------
__global__ __launch_bounds__(256) void k_wsplit(const float* __restrict__ W,
                                                unsigned short* __restrict__ Whi,
                                                unsigned short* __restrict__ Wlo, int total) {
    int i = blockIdx.x * 256 + threadIdx.x;
    if (i < total) {
        float f = W[i];
        unsigned int u = __float_as_uint(f);
        Whi[i] = (unsigned short)(u >> 16);
        Wlo[i] = (unsigned short)f2bf(f - __uint_as_float(u & 0xffff0000u));
    }
}

// ---------------- k_prep: V vectors (W^T a1, W^T a2) + constants ------------
__global__ __launch_bounds__(256) void k_prep(
    const float* __restrict__ fcsW, const float* __restrict__ fcsb,
    const float* __restrict__ a1, const float* __restrict__ a2,
    float* __restrict__ Vf, unsigned short* __restrict__ Vh,
    unsigned short* __restrict__ Vl, float* __restrict__ cvec) {
    int i = blockIdx.x;
    int t = threadIdx.x;
    const float* W = fcsW + (size_t)i * 16384;
    if (t < 128) {
        float s1 = 0.f, s2 = 0.f;
        for (int j = 0; j < 128; ++j) {
            float w = W[j * 128 + t];
            s1 = fmaf(w, a1[i * 128 + j], s1);
            s2 = fmaf(w, a2[i * 128 + j], s2);
        }
        Vf[i * 128 + t] = s1;
        Vf[(16 + i) * 128 + t] = s2;
        Vh[i * 128 + t] = (unsigned short)(__float_as_uint(s1) >> 16);
        Vl[i * 128 + t] = (unsigned short)f2bf(s1 - hi_part(s1));
        Vh[(16 + i) * 128 + t] = (unsigned short)(__float_as_uint(s2) >> 16);
        Vl[(16 + i) * 128 + t] = (unsigned short)f2bf(s2 - hi_part(s2));
    } else if (t == 128) {
        float c1 = 0.f, c2 = 0.f;
        for (int j = 0; j < 128; ++j) {
            c1 = fmaf(fcsb[i * 128 + j], a1[i * 128 + j], c1);
            c2 = fmaf(fcsb[i * 128 + j], a2[i * 128 + j], c2);
        }
        cvec[i] = c1;
        cvec[16 + i] = c2;
    }
}

// ---------------- fc1: 3-term, BM=32, staged dense stores ----------------
__global__ __launch_bounds__(256) void k_fc1(
    const float* __restrict__ Xf,
    const unsigned short* __restrict__ Wh, const unsigned short* __restrict__ Wl,
    const float* __restrict__ bias,
    unsigned short* __restrict__ Yhi, unsigned short* __restrict__ Ylo, int N) {
    __shared__ unsigned short Shi[32 * 128];  // 8 KB
    __shared__ unsigned short Slo[32 * 128];  // 8 KB
    const int tid = threadIdx.x;
    const int r0 = blockIdx.x * 32;
    const int lane = tid & 63;
    const int w = tid >> 6;
    const int wr = (w >> 1) * 16, wc = (w & 1) * 64;
    const int frow = lane & 15;
    const int fk = lane >> 4;
    const int q4 = lane >> 4;

    f32x4 acc[4];
#pragma unroll
    for (int j = 0; j < 4; ++j) acc[j] = (f32x4){0.f, 0.f, 0.f, 0.f};

    const float4 z4 = make_float4(0.f, 0.f, 0.f, 0.f);
#pragma unroll
    for (int kc = 0; kc < 8; ++kc) {
        int row = r0 + wr + frow;
        float4 va = z4, vb = z4;
        if (row < N) {
            const float* p = Xf + (size_t)row * 256 + kc * 32 + fk * 8;
            va = *(const float4*)p;
            vb = *(const float4*)(p + 4);
        }
        uint4 h = pack_hi(va, vb);
        uint4 l = pack_lo(va, vb);
        short8 ah = *(short8*)&h;
        short8 al = *(short8*)&l;
#pragma unroll
        for (int ci = 0; ci < 4; ++ci) {
            int col = wc + ci * 16 + frow;
            short8 bh = *(const short8*)(Wh + (size_t)col * 256 + kc * 32 + fk * 8);
            short8 bl = *(const short8*)(Wl + (size_t)col * 256 + kc * 32 + fk * 8);
            acc[ci] = MFMA16(ah, bh, acc[ci], 0, 0, 0);
            acc[ci] = MFMA16(ah, bl, acc[ci], 0, 0, 0);
            acc[ci] = MFMA16(al, bh, acc[ci], 0, 0, 0);
        }
    }

#pragma unroll
    for (int ci = 0; ci < 4; ++ci) {
        int col = wc + ci * 16 + frow;
        float bcol = bias[col];
        f32x4 v = acc[ci];
#pragma unroll
        for (int reg = 0; reg < 4; ++reg) {
            float val = fmaxf(v[reg] + bcol, 0.f);
            int row = wr + q4 * 4 + reg;
            int dw = (col >> 1) ^ ((row & 12) << 1);
            Shi[row * 128 + dw * 2 + (col & 1)] = (unsigned short)(__float_as_uint(val) >> 16);
            Slo[row * 128 + dw * 2 + (col & 1)] = (unsigned short)f2bf(val - hi_part(val));
        }
    }
    __syncthreads();
#pragma unroll
    for (int q = 0; q < 2; ++q) {
        int idx = q * 256 + tid;        // 0..511
        int row = idx >> 4;             // 0..31
        int gc = idx & 15;
        int dwb = (gc * 4) ^ ((row & 12) << 1);
        int grow = r0 + row;
        if (grow < N) {
            *(uint4*)(Yhi + (size_t)grow * 128 + gc * 8) = *(const uint4*)(Shi + row * 128 + dwb * 2);
            *(uint4*)(Ylo + (size_t)grow * 128 + gc * 8) = *(const uint4*)(Slo + row * 128 + dwb * 2);
        }
    }
}

// ---------------- k_xdots: x1a/xa2a for ALL hops in one N x 32 GEMM ---------
__global__ __launch_bounds__(256) void k_xdots(
    const unsigned short* __restrict__ Xhi, const unsigned short* __restrict__ Xlo,
    const unsigned short* __restrict__ Vh, const unsigned short* __restrict__ Vl,
    const float* __restrict__ cvec,
    float* __restrict__ x1a_all, float* __restrict__ xa2a_all, int N) {
    const int tid = threadIdx.x;
    const int r0 = blockIdx.x * 64;
    const int lane = tid & 63;
    const int w = tid >> 6;
    const int wr = w * 16;
    const int frow = lane & 15;
    const int fk = lane >> 4;
    const int q4 = lane >> 4;

    f32x4 acc[2];
    acc[0] = (f32x4){0.f, 0.f, 0.f, 0.f};
    acc[1] = (f32x4){0.f, 0.f, 0.f, 0.f};

    const short8 z8 = (short8){0, 0, 0, 0, 0, 0, 0, 0};
#pragma unroll
    for (int kc = 0; kc < 4; ++kc) {
        int row = r0 + wr + frow;
        bool ok = row < N;
        short8 ah = ok ? *(const short8*)(Xhi + (size_t)row * 128 + kc * 32 + fk * 8) : z8;
        short8 al = ok ? *(const short8*)(Xlo + (size_t)row * 128 + kc * 32 + fk * 8) : z8;
#pragma unroll
        for (int ci = 0; ci < 2; ++ci) {
            int col = ci * 16 + frow;
            short8 bh = *(const short8*)(Vh + (size_t)col * 128 + kc * 32 + fk * 8);
            short8 bl = *(const short8*)(Vl + (size_t)col * 128 + kc * 32 + fk * 8);
            acc[ci] = MFMA16(ah, bh, acc[ci], 0, 0, 0);
            acc[ci] = MFMA16(ah, bl, acc[ci], 0, 0, 0);
            acc[ci] = MFMA16(al, bh, acc[ci], 0, 0, 0);
        }
    }

#pragma unroll
    for (int ci = 0; ci < 2; ++ci) {
        int col = ci * 16 + frow;
        float c = cvec[col];
#pragma unroll
        for (int reg = 0; reg < 4; ++reg) {
            int grow = r0 + wr + q4 * 4 + reg;
            if (grow < N) {
                float val = acc[ci][reg] + c;
                if (col < 10) x1a_all[(size_t)col * N + grow] = val;
                else if (col >= 16 && col < 26) xa2a_all[(size_t)(col - 16) * N + grow] = val;
            }
        }
    }
}

// ---------------- k_hop: fused gather + GEMM, BM=32, 32-bit offsets ---------
__global__ __launch_bounds__(256) void k_hop(
    const unsigned short* __restrict__ table, const unsigned short* __restrict__ xh,
    const float* __restrict__ x1a, const float* __restrict__ xa2a,
    const float* __restrict__ h1in,
    const int* __restrict__ rp, const int* __restrict__ ts,
    const unsigned short* __restrict__ Wh, const unsigned short* __restrict__ Wl,
    const float* __restrict__ bias, const float* __restrict__ vnext,
    const float* __restrict__ cnextp,
    unsigned short* __restrict__ Hout, float* __restrict__ h1out, int N) {
    __shared__ unsigned short gS[32 * 128];  // 8 KB: g tile, then C-stage
    __shared__ uint2 ew[4][64];
    __shared__ float dotbuf[32][2];
    const int tid = threadIdx.x;
    const int wid = tid >> 6;
    const int lane = tid & 63;
    const int r0 = blockIdx.x * 32;
    const unsigned int lo2 = (unsigned int)(lane * 2);

    // ---- phase 1: each wave gathers 8 rows ----
    for (int j = 0; j < 8; ++j) {
        int gr = wid * 8 + j;
        int u = r0 + gr;
        unsigned int packed = 0u;
        if (u < N) {
            float x1u = x1a[u];
            float w2 = expf(lrelu02(x1u + xa2a[u]));
            float2 xr = bf2f2(*(const unsigned int*)(xh + (size_t)u * 128 + lo2));
            float accx = w2 * xr.x, accy = w2 * xr.y;
            float div = w2;
            int p0 = rp[u], p1 = rp[u + 1];
            for (int base = p0; base < p1; base += 64) {
                int e = base + lane;
                uint2 pk = make_uint2(0u, 0u);
                if (e < p1) {
                    unsigned int tv = (unsigned int)ts[e];  // pre-scaled t*128
                    pk.x = tv;
                    pk.y = __float_as_uint(expf(lrelu02(x1u + h1in[tv >> 7])));
                }
                ew[wid][lane] = pk;
                int m = p1 - base; if (m > 64) m = 64;
                int m8 = (m + 7) & ~7;
                for (int jj = 0; jj < m8; jj += 8) {
                    uint2 q[8];
#pragma unroll
                    for (int k = 0; k < 8; ++k) q[k] = ew[wid][jj + k];
                    unsigned int hv[8];
#pragma unroll
                    for (int k = 0; k < 8; ++k)
                        hv[k] = *(const unsigned int*)(table + (q[k].x + lo2));
#pragma unroll
                    for (int k = 0; k < 8; ++k) {
                        float ww = __uint_as_float(q[k].y);
                        float2 f = bf2f2(hv[k]);
                        accx = fmaf(ww, f.x, accx);
                        accy = fmaf(ww, f.y, accy);
                        div += ww;
                    }
                }
            }
            float ox = accx / div, oy = accy / div;
            packed = f2bf(ox) | (f2bf(oy) << 16);
        }
        int dw = (((lane >> 2) ^ (gr & 7)) << 2) | (lane & 3);
        *((unsigned int*)gS + gr * 64 + dw) = packed;
    }
    __syncthreads();

    // ---- phase 2: GEMM (wave = 16 rows x 64 cols) ----
    const int w = wid;
    const int wr = (w >> 1) * 16, wc = (w & 1) * 64;
    const int frow = lane & 15;
    const int fk = lane >> 4;
    const int q4 = lane >> 4;
    const bool dodot = vnext != nullptr;

    f32x4 acc[4];
#pragma unroll
    for (int j = 0; j < 4; ++j) acc[j] = (f32x4){0.f, 0.f, 0.f, 0.f};

#pragma unroll
    for (int kc = 0; kc < 4; ++kc) {
        int row = wr + frow;
        int gg = kc * 4 + fk;
        short8 ah = *(const short8*)(gS + row * 128 + ((gg ^ (row & 7)) * 8));
#pragma unroll
        for (int ci = 0; ci < 4; ++ci) {
            int col = wc + ci * 16 + frow;
            short8 bh = *(const short8*)(Wh + (size_t)col * 128 + kc * 32 + fk * 8);
            short8 bl = *(const short8*)(Wl + (size_t)col * 128 + kc * 32 + fk * 8);
            acc[ci] = MFMA16(ah, bh, acc[ci], 0, 0, 0);
            acc[ci] = MFMA16(ah, bl, acc[ci], 0, 0, 0);
        }
    }
    __syncthreads();  // all A-frag reads done; gS becomes C-stage

    float dotA[4] = {};
#pragma unroll
    for (int ci = 0; ci < 4; ++ci) {
        int col = wc + ci * 16 + frow;
        float bcol = bias[col];
        float vc = dodot ? vnext[col] : 0.f;
        f32x4 v = acc[ci];
#pragma unroll
        for (int reg = 0; reg < 4; ++reg) {
            float val = v[reg] + bcol;
            val = val > 0.f ? val : expf(val) - 1.f;  // elu
            int row = wr + q4 * 4 + reg;
            int dw = (col >> 1) ^ ((row & 12) << 1);
            gS[row * 128 + dw * 2 + (col & 1)] = (unsigned short)f2bf(val);
            dotA[reg] = fmaf(val, vc, dotA[reg]);
        }
    }
#pragma unroll
    for (int m = 1; m < 16; m <<= 1)
#pragma unroll
        for (int reg = 0; reg < 4; ++reg)
            dotA[reg] += __shfl_xor(dotA[reg], m, 64);
    if (frow == 0) {
#pragma unroll
        for (int reg = 0; reg < 4; ++reg) {
            int rl = wr + q4 * 4 + reg;
            dotbuf[rl][w & 1] = dotA[reg];
        }
    }
    __syncthreads();

#pragma unroll
    for (int q = 0; q < 2; ++q) {
        int idx = q * 256 + tid;        // 0..511
        int row = idx >> 4;             // 0..31
        int gc = idx & 15;
        int dwb = (gc * 4) ^ ((row & 12) << 1);
        uint4 vv = *(const uint4*)(gS + row * 128 + dwb * 2);
        int grow = r0 + row;
        if (grow < N) *(uint4*)(Hout + (size_t)grow * 128 + gc * 8) = vv;
    }
    if (dodot && tid < 32) {
        int grow = r0 + tid;
        if (grow < N) h1out[grow] = dotbuf[tid][0] + dotbuf[tid][1] + cnextp[0];
    }
}

// ---------------- fc2: barrier-free, zero-LDS, 2-term, BM=64 ----------------
__global__ __launch_bounds__(256) void k_fc2(
    const unsigned short* __restrict__ Xhi,
    const unsigned short* __restrict__ Wh, const unsigned short* __restrict__ Wl,
    const float* __restrict__ bias, float* __restrict__ Yf, int N) {
    const int tid = threadIdx.x;
    const int r0 = blockIdx.x * 64;
    const int lane = tid & 63;
    const int w = tid >> 6;
    const int wr = w * 16;
    const int frow = lane & 15;
    const int fk = lane >> 4;
    const int q4 = lane >> 4;

    f32x4 acc[4];
#pragma unroll
    for (int j = 0; j < 4; ++j) acc[j] = (f32x4){0.f, 0.f, 0.f, 0.f};

    const short8 z8 = (short8){0, 0, 0, 0, 0, 0, 0, 0};
#pragma unroll
    for (int kc = 0; kc < 4; ++kc) {
        int row = r0 + wr + frow;
        short8 ah = (row < N) ? *(const short8*)(Xhi + (size_t)row * 128 + kc * 32 + fk * 8) : z8;
#pragma unroll
        for (int ci = 0; ci < 4; ++ci) {
            int col = ci * 16 + frow;
            short8 bh = *(const short8*)(Wh + (size_t)col * 128 + kc * 32 + fk * 8);
            short8 bl = *(const short8*)(Wl + (size_t)col * 128 + kc * 32 + fk * 8);
            acc[ci] = MFMA16(ah, bh, acc[ci], 0, 0, 0);
            acc[ci] = MFMA16(ah, bl, acc[ci], 0, 0, 0);
        }
    }

#pragma unroll
    for (int ci = 0; ci < 4; ++ci) {
        int col = ci * 16 + frow;
        float bcol = bias[col];
#pragma unroll
        for (int reg = 0; reg < 4; ++reg) {
            int grow = r0 + wr + q4 * 4 + reg;
            if (grow < N) Yf[(size_t)grow * 64 + col] = acc[ci][reg] + bcol;
        }
    }
}

// ---------------- launch ----------------
extern "C" void kernel_launch(void* const* d_in, const int* in_sizes, int n_in,
                              void* d_out, int out_size, void* d_ws, size_t ws_size,
                              hipStream_t stream) {
    const float* x_in = (const float*)d_in[0];
    const int*   s    = (const int*)d_in[1];
    const int*   t    = (const int*)d_in[2];
    const float* fc1W = (const float*)d_in[3];
    const float* fc1b = (const float*)d_in[4];
    const float* fcsW = (const float*)d_in[5];
    const float* fcsb = (const float*)d_in[6];
    const float* a1   = (const float*)d_in[7];
    const float* a2   = (const float*)d_in[8];
    const float* fc2W = (const float*)d_in[9];
    const float* fc2b = (const float*)d_in[10];

    const int N = in_sizes[0] / 256;  // 50000
    const int E = in_sizes[1];        // 800000
    const int G = (N + 255) / 256;
    const int NB64 = (N + 63) / 64;   // 782
    const int NB32 = (N + 31) / 32;   // 1563

    char* ws = (char*)d_ws;
    size_t off = 0;
    auto alloc = [&](size_t bytes) -> void* {
        void* p = ws + off;
        off += (bytes + 255) & ~(size_t)255;
        return p;
    };
    unsigned short* xbuf_hi = (unsigned short*)alloc((size_t)N * 128 * 2);
    unsigned short* xbuf_lo = (unsigned short*)alloc((size_t)N * 128 * 2);
    unsigned short* hA      = (unsigned short*)alloc((size_t)N * 128 * 2);
    unsigned short* hB      = (unsigned short*)alloc((size_t)N * 128 * 2);
    unsigned short* Whi  = (unsigned short*)alloc((size_t)10 * 16384 * 2);
    unsigned short* Wlo  = (unsigned short*)alloc((size_t)10 * 16384 * 2);
    unsigned short* W1hi = (unsigned short*)alloc((size_t)128 * 256 * 2);
    unsigned short* W1lo = (unsigned short*)alloc((size_t)128 * 256 * 2);
    unsigned short* W2hi = (unsigned short*)alloc((size_t)64 * 128 * 2);
    unsigned short* W2lo = (unsigned short*)alloc((size_t)64 * 128 * 2);
    float* Vf   = (float*)alloc((size_t)32 * 128 * 4);
    unsigned short* Vh = (unsigned short*)alloc((size_t)32 * 128 * 2);
    unsigned short* Vl = (unsigned short*)alloc((size_t)32 * 128 * 2);
    float* cvec = (float*)alloc((size_t)32 * 4);
    float* x1a_all  = (float*)alloc((size_t)10 * N * 4);
    float* xa2a_all = (float*)alloc((size_t)10 * N * 4);
    float* h1aA = (float*)alloc((size_t)N * 4);
    float* h1aB = (float*)alloc((size_t)N * 4);
    int* row_ptr  = (int*)alloc((size_t)(N + 1) * 4);
    int* cnt      = (int*)alloc((size_t)N * 4);
    int* bsums    = (int*)alloc((size_t)1024);
    int* t_sorted = (int*)alloc((size_t)E * 4);

    // CSR build
    hipMemsetAsync(cnt, 0, (size_t)N * 4, stream);
    k_count<<<(E + 255) / 256, 256, 0, stream>>>(s, cnt, E);
    k_scan1<<<G, 256, 0, stream>>>(cnt, bsums, N);
    k_scan2<<<1, 256, 0, stream>>>(bsums, G);
    k_scan3<<<G, 256, 0, stream>>>(cnt, bsums, row_ptr, N);
    hipMemsetAsync(cnt, 0, (size_t)N * 4, stream);
    k_scatter<<<(E + 255) / 256, 256, 0, stream>>>(s, t, row_ptr, cnt, t_sorted, E);

    // W splits + V prep
    k_wsplit<<<(10 * 16384 + 255) / 256, 256, 0, stream>>>(fcsW, Whi, Wlo, 10 * 16384);
    k_wsplit<<<(128 * 256 + 255) / 256, 256, 0, stream>>>(fc1W, W1hi, W1lo, 128 * 256);
    k_wsplit<<<(64 * 128 + 255) / 256, 256, 0, stream>>>(fc2W, W2hi, W2lo, 64 * 128);
    hipMemsetAsync(Vf, 0, (size_t)32 * 128 * 4, stream);
    hipMemsetAsync(Vh, 0, (size_t)32 * 128 * 2, stream);
    hipMemsetAsync(Vl, 0, (size_t)32 * 128 * 2, stream);
    hipMemsetAsync(cvec, 0, (size_t)32 * 4, stream);
    k_prep<<<10, 256, 0, stream>>>(fcsW, fcsb, a1, a2, Vf, Vh, Vl, cvec);

    // fc1 + relu -> split planes (BM=32)
    k_fc1<<<NB32, 256, 0, stream>>>(x_in, W1hi, W1lo, fc1b, xbuf_hi, xbuf_lo, N);

    // x-side scalars for all hops
    k_xdots<<<NB64, 256, 0, stream>>>(xbuf_hi, xbuf_lo, Vh, Vl, cvec,
                                      x1a_all, xa2a_all, N);

    // hops: fused gather + GEMM, ping-pong h / h1a
    const unsigned short* table = xbuf_hi;
    const float* h1in = xa2a_all;  // hop 0: h1 == xa2 (h == x)
    for (int i = 0; i < 10; ++i) {
        unsigned short* hout = (i & 1) ? hB : hA;
        float* h1out = (i & 1) ? h1aB : h1aA;
        const float* vnext = (i < 9) ? (Vf + (size_t)(16 + i + 1) * 128) : nullptr;
        k_hop<<<NB32, 256, 0, stream>>>(table, xbuf_hi,
                                        x1a_all + (size_t)i * N, xa2a_all + (size_t)i * N,
                                        h1in, row_ptr, t_sorted,
                                        Whi + (size_t)i * 16384, Wlo + (size_t)i * 16384,
                                        fcsb + (size_t)i * 128, vnext, cvec + (16 + i + 1),
                                        hout, h1out, N);
        table = hout;
        h1in = h1out;
    }

    // fc2
    k_fc2<<<NB64, 256, 0, stream>>>(table, W2hi, W2lo, fc2b, (float*)d_out, N);
}

// Round 18
// 752.367 us; speedup vs baseline: 1.0862x; 1.0190x over previous
//
#include <hip/hip_runtime.h>
#include <math.h>

// ---------------------------------------------------------------------------
// GTAN2 R18: R17 with fc1 reverted to BM=64 (R15 form). R17's fc1 BM=32
// halved arithmetic intensity (same W-loads per wave, half the MFMA) and
// regressed 44->73us. Keep R17's 32-bit pre-scaled gather offsets in k_hop.
// ---------------------------------------------------------------------------

typedef __attribute__((ext_vector_type(8))) short short8;
typedef __attribute__((ext_vector_type(4))) float f32x4;
#define MFMA16 __builtin_amdgcn_mfma_f32_16x16x32_bf16

__device__ __forceinline__ float lrelu02(float v) { return v > 0.f ? v : 0.2f * v; }

__device__ __forceinline__ float2 bf2f2(unsigned int v) {
    return make_float2(__uint_as_float(v << 16), __uint_as_float(v & 0xffff0000u));
}
__device__ __forceinline__ unsigned int f2bf(float f) {  // RNE bf16
    unsigned int u = __float_as_uint(f);
    u += 0x7fffu + ((u >> 16) & 1u);
    return u >> 16;
}
__device__ __forceinline__ float hi_part(float f) {
    return __uint_as_float(__float_as_uint(f) & 0xffff0000u);
}
__device__ __forceinline__ uint4 pack_hi(const float4& a, const float4& b) {
    uint4 r;
    r.x = (__float_as_uint(a.x) >> 16) | (__float_as_uint(a.y) & 0xffff0000u);
    r.y = (__float_as_uint(a.z) >> 16) | (__float_as_uint(a.w) & 0xffff0000u);
    r.z = (__float_as_uint(b.x) >> 16) | (__float_as_uint(b.y) & 0xffff0000u);
    r.w = (__float_as_uint(b.z) >> 16) | (__float_as_uint(b.w) & 0xffff0000u);
    return r;
}
__device__ __forceinline__ uint4 pack_lo(const float4& a, const float4& b) {
    uint4 r;
    r.x = f2bf(a.x - hi_part(a.x)) | (f2bf(a.y - hi_part(a.y)) << 16);
    r.y = f2bf(a.z - hi_part(a.z)) | (f2bf(a.w - hi_part(a.w)) << 16);
    r.z = f2bf(b.x - hi_part(b.x)) | (f2bf(b.y - hi_part(b.y)) << 16);
    r.w = f2bf(b.z - hi_part(b.z)) | (f2bf(b.w - hi_part(b.w)) << 16);
    return r;
}

// ---------------- CSR build ----------------
__global__ __launch_bounds__(256) void k_count(const int* __restrict__ s, int* __restrict__ cnt, int E) {
    int e = blockIdx.x * 256 + threadIdx.x;
    if (e < E) atomicAdd(&cnt[s[e]], 1);
}

__global__ __launch_bounds__(256) void k_scan1(const int* __restrict__ cnt, int* __restrict__ bs, int N) {
    __shared__ int sh[256];
    int idx = blockIdx.x * 256 + threadIdx.x;
    sh[threadIdx.x] = (idx < N) ? cnt[idx] : 0;
    __syncthreads();
#pragma unroll
    for (int off = 128; off; off >>= 1) {
        if (threadIdx.x < off) sh[threadIdx.x] += sh[threadIdx.x + off];
        __syncthreads();
    }
    if (threadIdx.x == 0) bs[blockIdx.x] = sh[0];
}

__global__ __launch_bounds__(256) void k_scan2(int* __restrict__ bs, int G) {
    __shared__ int sh[256];
    int t = threadIdx.x;
    int v = (t < G) ? bs[t] : 0;
    sh[t] = v;
    __syncthreads();
    int val = v;
#pragma unroll
    for (int off = 1; off < 256; off <<= 1) {
        int o = (t >= off) ? sh[t - off] : 0;
        __syncthreads();
        val += o; sh[t] = val;
        __syncthreads();
    }
    if (t < G) bs[t] = val - v;  // exclusive
}

__global__ __launch_bounds__(256) void k_scan3(const int* __restrict__ cnt, const int* __restrict__ bs,
                                               int* __restrict__ rp, int N) {
    __shared__ int sh[256];
    int t = threadIdx.x;
    int idx = blockIdx.x * 256 + t;
    int v = (idx < N) ? cnt[idx] : 0;
    sh[t] = v;
    __syncthreads();
    int val = v;
#pragma unroll
    for (int off = 1; off < 256; off <<= 1) {
        int o = (t >= off) ? sh[t - off] : 0;
        __syncthreads();
        val += o; sh[t] = val;
        __syncthreads();
    }
    if (idx <= N) rp[idx] = val - v + bs[blockIdx.x];
}

// t_sorted stores t*128 (ushort-element offset of the row) for 32-bit addressing
__global__ __launch_bounds__(256) void k_scatter(const int* __restrict__ s, const int* __restrict__ t,
                                                 const int* __restrict__ rp, int* __restrict__ cursor,
                                                 int* __restrict__ t_sorted, int E) {
    int e = blockIdx.x * 256 + threadIdx.x;
    if (e < E) {
        int u = s[e];
        int pos = atomicAdd(&cursor[u], 1);
        t_sorted[rp[u] + pos] = t[e] << 7;
    }
}

// ---------------- W split ----------------
__global__ __launch_bounds__(256) void k_wsplit(const float* __restrict__ W,
                                                unsigned short* __restrict__ Whi,
                                                unsigned short* __restrict__ Wlo, int total) {
    int i = blockIdx.x * 256 + threadIdx.x;
    if (i < total) {
        float f = W[i];
        unsigned int u = __float_as_uint(f);
        Whi[i] = (unsigned short)(u >> 16);
        Wlo[i] = (unsigned short)f2bf(f - __uint_as_float(u & 0xffff0000u));
    }
}

// ---------------- k_prep: V vectors (W^T a1, W^T a2) + constants ------------
__global__ __launch_bounds__(256) void k_prep(
    const float* __restrict__ fcsW, const float* __restrict__ fcsb,
    const float* __restrict__ a1, const float* __restrict__ a2,
    float* __restrict__ Vf, unsigned short* __restrict__ Vh,
    unsigned short* __restrict__ Vl, float* __restrict__ cvec) {
    int i = blockIdx.x;
    int t = threadIdx.x;
    const float* W = fcsW + (size_t)i * 16384;
    if (t < 128) {
        float s1 = 0.f, s2 = 0.f;
        for (int j = 0; j < 128; ++j) {
            float w = W[j * 128 + t];
            s1 = fmaf(w, a1[i * 128 + j], s1);
            s2 = fmaf(w, a2[i * 128 + j], s2);
        }
        Vf[i * 128 + t] = s1;
        Vf[(16 + i) * 128 + t] = s2;
        Vh[i * 128 + t] = (unsigned short)(__float_as_uint(s1) >> 16);
        Vl[i * 128 + t] = (unsigned short)f2bf(s1 - hi_part(s1));
        Vh[(16 + i) * 128 + t] = (unsigned short)(__float_as_uint(s2) >> 16);
        Vl[(16 + i) * 128 + t] = (unsigned short)f2bf(s2 - hi_part(s2));
    } else if (t == 128) {
        float c1 = 0.f, c2 = 0.f;
        for (int j = 0; j < 128; ++j) {
            c1 = fmaf(fcsb[i * 128 + j], a1[i * 128 + j], c1);
            c2 = fmaf(fcsb[i * 128 + j], a2[i * 128 + j], c2);
        }
        cvec[i] = c1;
        cvec[16 + i] = c2;
    }
}

// ---------------- fc1: 3-term, BM=64, staged dense stores (R15 form) --------
__global__ __launch_bounds__(256) void k_fc1(
    const float* __restrict__ Xf,
    const unsigned short* __restrict__ Wh, const unsigned short* __restrict__ Wl,
    const float* __restrict__ bias,
    unsigned short* __restrict__ Yhi, unsigned short* __restrict__ Ylo, int N) {
    __shared__ unsigned short Shi[64 * 128];
    __shared__ unsigned short Slo[64 * 128];
    const int tid = threadIdx.x;
    const int r0 = blockIdx.x * 64;
    const int lane = tid & 63;
    const int w = tid >> 6;
    const int wr = (w >> 1) * 32, wc = (w & 1) * 64;
    const int frow = lane & 15;
    const int fk = lane >> 4;
    const int q4 = lane >> 4;

    f32x4 acc[2][4];
#pragma unroll
    for (int i = 0; i < 2; ++i)
#pragma unroll
        for (int j = 0; j < 4; ++j) acc[i][j] = (f32x4){0.f, 0.f, 0.f, 0.f};

    const float4 z4 = make_float4(0.f, 0.f, 0.f, 0.f);
#pragma unroll
    for (int kc = 0; kc < 8; ++kc) {
        short8 ah[2], al[2];
#pragma unroll
        for (int ri = 0; ri < 2; ++ri) {
            int row = r0 + wr + ri * 16 + frow;
            float4 va = z4, vb = z4;
            if (row < N) {
                const float* p = Xf + (size_t)row * 256 + kc * 32 + fk * 8;
                va = *(const float4*)p;
                vb = *(const float4*)(p + 4);
            }
            uint4 h = pack_hi(va, vb);
            uint4 l = pack_lo(va, vb);
            ah[ri] = *(short8*)&h;
            al[ri] = *(short8*)&l;
        }
#pragma unroll
        for (int ci = 0; ci < 4; ++ci) {
            int col = wc + ci * 16 + frow;
            short8 bh = *(const short8*)(Wh + (size_t)col * 256 + kc * 32 + fk * 8);
            short8 bl = *(const short8*)(Wl + (size_t)col * 256 + kc * 32 + fk * 8);
#pragma unroll
            for (int ri = 0; ri < 2; ++ri) {
                acc[ri][ci] = MFMA16(ah[ri], bh, acc[ri][ci], 0, 0, 0);
                acc[ri][ci] = MFMA16(ah[ri], bl, acc[ri][ci], 0, 0, 0);
                acc[ri][ci] = MFMA16(al[ri], bh, acc[ri][ci], 0, 0, 0);
            }
        }
    }

#pragma unroll
    for (int ci = 0; ci < 4; ++ci) {
        int col = wc + ci * 16 + frow;
        float bcol = bias[col];
#pragma unroll
        for (int ri = 0; ri < 2; ++ri) {
            f32x4 v = acc[ri][ci];
#pragma unroll
            for (int reg = 0; reg < 4; ++reg) {
                float val = fmaxf(v[reg] + bcol, 0.f);
                int row = wr + ri * 16 + q4 * 4 + reg;
                int dw = (col >> 1) ^ ((row & 12) << 1);
                Shi[row * 128 + dw * 2 + (col & 1)] = (unsigned short)(__float_as_uint(val) >> 16);
                Slo[row * 128 + dw * 2 + (col & 1)] = (unsigned short)f2bf(val - hi_part(val));
            }
        }
    }
    __syncthreads();
#pragma unroll
    for (int q = 0; q < 4; ++q) {
        int idx = q * 256 + tid;
        int row = idx >> 4;
        int gc = idx & 15;
        int dwb = (gc * 4) ^ ((row & 12) << 1);
        int grow = r0 + row;
        if (grow < N) {
            *(uint4*)(Yhi + (size_t)grow * 128 + gc * 8) = *(const uint4*)(Shi + row * 128 + dwb * 2);
            *(uint4*)(Ylo + (size_t)grow * 128 + gc * 8) = *(const uint4*)(Slo + row * 128 + dwb * 2);
        }
    }
}

// ---------------- k_xdots: x1a/xa2a for ALL hops in one N x 32 GEMM ---------
__global__ __launch_bounds__(256) void k_xdots(
    const unsigned short* __restrict__ Xhi, const unsigned short* __restrict__ Xlo,
    const unsigned short* __restrict__ Vh, const unsigned short* __restrict__ Vl,
    const float* __restrict__ cvec,
    float* __restrict__ x1a_all, float* __restrict__ xa2a_all, int N) {
    const int tid = threadIdx.x;
    const int r0 = blockIdx.x * 64;
    const int lane = tid & 63;
    const int w = tid >> 6;
    const int wr = w * 16;
    const int frow = lane & 15;
    const int fk = lane >> 4;
    const int q4 = lane >> 4;

    f32x4 acc[2];
    acc[0] = (f32x4){0.f, 0.f, 0.f, 0.f};
    acc[1] = (f32x4){0.f, 0.f, 0.f, 0.f};

    const short8 z8 = (short8){0, 0, 0, 0, 0, 0, 0, 0};
#pragma unroll
    for (int kc = 0; kc < 4; ++kc) {
        int row = r0 + wr + frow;
        bool ok = row < N;
        short8 ah = ok ? *(const short8*)(Xhi + (size_t)row * 128 + kc * 32 + fk * 8) : z8;
        short8 al = ok ? *(const short8*)(Xlo + (size_t)row * 128 + kc * 32 + fk * 8) : z8;
#pragma unroll
        for (int ci = 0; ci < 2; ++ci) {
            int col = ci * 16 + frow;
            short8 bh = *(const short8*)(Vh + (size_t)col * 128 + kc * 32 + fk * 8);
            short8 bl = *(const short8*)(Vl + (size_t)col * 128 + kc * 32 + fk * 8);
            acc[ci] = MFMA16(ah, bh, acc[ci], 0, 0, 0);
            acc[ci] = MFMA16(ah, bl, acc[ci], 0, 0, 0);
            acc[ci] = MFMA16(al, bh, acc[ci], 0, 0, 0);
        }
    }

#pragma unroll
    for (int ci = 0; ci < 2; ++ci) {
        int col = ci * 16 + frow;
        float c = cvec[col];
#pragma unroll
        for (int reg = 0; reg < 4; ++reg) {
            int grow = r0 + wr + q4 * 4 + reg;
            if (grow < N) {
                float val = acc[ci][reg] + c;
                if (col < 10) x1a_all[(size_t)col * N + grow] = val;
                else if (col >= 16 && col < 26) xa2a_all[(size_t)(col - 16) * N + grow] = val;
            }
        }
    }
}

// ---------------- k_hop: fused gather + GEMM, BM=32, 32-bit offsets ---------
__global__ __launch_bounds__(256) void k_hop(
    const unsigned short* __restrict__ table, const unsigned short* __restrict__ xh,
    const float* __restrict__ x1a, const float* __restrict__ xa2a,
    const float* __restrict__ h1in,
    const int* __restrict__ rp, const int* __restrict__ ts,
    const unsigned short* __restrict__ Wh, const unsigned short* __restrict__ Wl,
    const float* __restrict__ bias, const float* __restrict__ vnext,
    const float* __restrict__ cnextp,
    unsigned short* __restrict__ Hout, float* __restrict__ h1out, int N) {
    __shared__ unsigned short gS[32 * 128];  // 8 KB: g tile, then C-stage
    __shared__ uint2 ew[4][64];
    __shared__ float dotbuf[32][2];
    const int tid = threadIdx.x;
    const int wid = tid >> 6;
    const int lane = tid & 63;
    const int r0 = blockIdx.x * 32;
    const unsigned int lo2 = (unsigned int)(lane * 2);

    // ---- phase 1: each wave gathers 8 rows ----
    for (int j = 0; j < 8; ++j) {
        int gr = wid * 8 + j;
        int u = r0 + gr;
        unsigned int packed = 0u;
        if (u < N) {
            float x1u = x1a[u];
            float w2 = expf(lrelu02(x1u + xa2a[u]));
            float2 xr = bf2f2(*(const unsigned int*)(xh + (size_t)u * 128 + lo2));
            float accx = w2 * xr.x, accy = w2 * xr.y;
            float div = w2;
            int p0 = rp[u], p1 = rp[u + 1];
            for (int base = p0; base < p1; base += 64) {
                int e = base + lane;
                uint2 pk = make_uint2(0u, 0u);
                if (e < p1) {
                    unsigned int tv = (unsigned int)ts[e];  // pre-scaled t*128
                    pk.x = tv;
                    pk.y = __float_as_uint(expf(lrelu02(x1u + h1in[tv >> 7])));
                }
                ew[wid][lane] = pk;
                int m = p1 - base; if (m > 64) m = 64;
                int m8 = (m + 7) & ~7;
                for (int jj = 0; jj < m8; jj += 8) {
                    uint2 q[8];
#pragma unroll
                    for (int k = 0; k < 8; ++k) q[k] = ew[wid][jj + k];
                    unsigned int hv[8];
#pragma unroll
                    for (int k = 0; k < 8; ++k)
                        hv[k] = *(const unsigned int*)(table + (q[k].x + lo2));
#pragma unroll
                    for (int k = 0; k < 8; ++k) {
                        float ww = __uint_as_float(q[k].y);
                        float2 f = bf2f2(hv[k]);
                        accx = fmaf(ww, f.x, accx);
                        accy = fmaf(ww, f.y, accy);
                        div += ww;
                    }
                }
            }
            float ox = accx / div, oy = accy / div;
            packed = f2bf(ox) | (f2bf(oy) << 16);
        }
        int dw = (((lane >> 2) ^ (gr & 7)) << 2) | (lane & 3);
        *((unsigned int*)gS + gr * 64 + dw) = packed;
    }
    __syncthreads();

    // ---- phase 2: GEMM (wave = 16 rows x 64 cols) ----
    const int w = wid;
    const int wr = (w >> 1) * 16, wc = (w & 1) * 64;
    const int frow = lane & 15;
    const int fk = lane >> 4;
    const int q4 = lane >> 4;
    const bool dodot = vnext != nullptr;

    f32x4 acc[4];
#pragma unroll
    for (int j = 0; j < 4; ++j) acc[j] = (f32x4){0.f, 0.f, 0.f, 0.f};

#pragma unroll
    for (int kc = 0; kc < 4; ++kc) {
        int row = wr + frow;
        int gg = kc * 4 + fk;
        short8 ah = *(const short8*)(gS + row * 128 + ((gg ^ (row & 7)) * 8));
#pragma unroll
        for (int ci = 0; ci < 4; ++ci) {
            int col = wc + ci * 16 + frow;
            short8 bh = *(const short8*)(Wh + (size_t)col * 128 + kc * 32 + fk * 8);
            short8 bl = *(const short8*)(Wl + (size_t)col * 128 + kc * 32 + fk * 8);
            acc[ci] = MFMA16(ah, bh, acc[ci], 0, 0, 0);
            acc[ci] = MFMA16(ah, bl, acc[ci], 0, 0, 0);
        }
    }
    __syncthreads();  // all A-frag reads done; gS becomes C-stage

    float dotA[4] = {};
#pragma unroll
    for (int ci = 0; ci < 4; ++ci) {
        int col = wc + ci * 16 + frow;
        float bcol = bias[col];
        float vc = dodot ? vnext[col] : 0.f;
        f32x4 v = acc[ci];
#pragma unroll
        for (int reg = 0; reg < 4; ++reg) {
            float val = v[reg] + bcol;
            val = val > 0.f ? val : expf(val) - 1.f;  // elu
            int row = wr + q4 * 4 + reg;
            int dw = (col >> 1) ^ ((row & 12) << 1);
            gS[row * 128 + dw * 2 + (col & 1)] = (unsigned short)f2bf(val);
            dotA[reg] = fmaf(val, vc, dotA[reg]);
        }
    }
#pragma unroll
    for (int m = 1; m < 16; m <<= 1)
#pragma unroll
        for (int reg = 0; reg < 4; ++reg)
            dotA[reg] += __shfl_xor(dotA[reg], m, 64);
    if (frow == 0) {
#pragma unroll
        for (int reg = 0; reg < 4; ++reg) {
            int rl = wr + q4 * 4 + reg;
            dotbuf[rl][w & 1] = dotA[reg];
        }
    }
    __syncthreads();

#pragma unroll
    for (int q = 0; q < 2; ++q) {
        int idx = q * 256 + tid;        // 0..511
        int row = idx >> 4;             // 0..31
        int gc = idx & 15;
        int dwb = (gc * 4) ^ ((row & 12) << 1);
        uint4 vv = *(const uint4*)(gS + row * 128 + dwb * 2);
        int grow = r0 + row;
        if (grow < N) *(uint4*)(Hout + (size_t)grow * 128 + gc * 8) = vv;
    }
    if (dodot && tid < 32) {
        int grow = r0 + tid;
        if (grow < N) h1out[grow] = dotbuf[tid][0] + dotbuf[tid][1] + cnextp[0];
    }
}

// ---------------- fc2: barrier-free, zero-LDS, 2-term, BM=64 ----------------
__global__ __launch_bounds__(256) void k_fc2(
    const unsigned short* __restrict__ Xhi,
    const unsigned short* __restrict__ Wh, const unsigned short* __restrict__ Wl,
    const float* __restrict__ bias, float* __restrict__ Yf, int N) {
    const int tid = threadIdx.x;
    const int r0 = blockIdx.x * 64;
    const int lane = tid & 63;
    const int w = tid >> 6;
    const int wr = w * 16;
    const int frow = lane & 15;
    const int fk = lane >> 4;
    const int q4 = lane >> 4;

    f32x4 acc[4];
#pragma unroll
    for (int j = 0; j < 4; ++j) acc[j] = (f32x4){0.f, 0.f, 0.f, 0.f};

    const short8 z8 = (short8){0, 0, 0, 0, 0, 0, 0, 0};
#pragma unroll
    for (int kc = 0; kc < 4; ++kc) {
        int row = r0 + wr + frow;
        short8 ah = (row < N) ? *(const short8*)(Xhi + (size_t)row * 128 + kc * 32 + fk * 8) : z8;
#pragma unroll
        for (int ci = 0; ci < 4; ++ci) {
            int col = ci * 16 + frow;
            short8 bh = *(const short8*)(Wh + (size_t)col * 128 + kc * 32 + fk * 8);
            short8 bl = *(const short8*)(Wl + (size_t)col * 128 + kc * 32 + fk * 8);
            acc[ci] = MFMA16(ah, bh, acc[ci], 0, 0, 0);
            acc[ci] = MFMA16(ah, bl, acc[ci], 0, 0, 0);
        }
    }

#pragma unroll
    for (int ci = 0; ci < 4; ++ci) {
        int col = ci * 16 + frow;
        float bcol = bias[col];
#pragma unroll
        for (int reg = 0; reg < 4; ++reg) {
            int grow = r0 + wr + q4 * 4 + reg;
            if (grow < N) Yf[(size_t)grow * 64 + col] = acc[ci][reg] + bcol;
        }
    }
}

// ---------------- launch ----------------
extern "C" void kernel_launch(void* const* d_in, const int* in_sizes, int n_in,
                              void* d_out, int out_size, void* d_ws, size_t ws_size,
                              hipStream_t stream) {
    const float* x_in = (const float*)d_in[0];
    const int*   s    = (const int*)d_in[1];
    const int*   t    = (const int*)d_in[2];
    const float* fc1W = (const float*)d_in[3];
    const float* fc1b = (const float*)d_in[4];
    const float* fcsW = (const float*)d_in[5];
    const float* fcsb = (const float*)d_in[6];
    const float* a1   = (const float*)d_in[7];
    const float* a2   = (const float*)d_in[8];
    const float* fc2W = (const float*)d_in[9];
    const float* fc2b = (const float*)d_in[10];

    const int N = in_sizes[0] / 256;  // 50000
    const int E = in_sizes[1];        // 800000
    const int G = (N + 255) / 256;
    const int NB64 = (N + 63) / 64;   // 782
    const int NB32 = (N + 31) / 32;   // 1563

    char* ws = (char*)d_ws;
    size_t off = 0;
    auto alloc = [&](size_t bytes) -> void* {
        void* p = ws + off;
        off += (bytes + 255) & ~(size_t)255;
        return p;
    };
    unsigned short* xbuf_hi = (unsigned short*)alloc((size_t)N * 128 * 2);
    unsigned short* xbuf_lo = (unsigned short*)alloc((size_t)N * 128 * 2);
    unsigned short* hA      = (unsigned short*)alloc((size_t)N * 128 * 2);
    unsigned short* hB      = (unsigned short*)alloc((size_t)N * 128 * 2);
    unsigned short* Whi  = (unsigned short*)alloc((size_t)10 * 16384 * 2);
    unsigned short* Wlo  = (unsigned short*)alloc((size_t)10 * 16384 * 2);
    unsigned short* W1hi = (unsigned short*)alloc((size_t)128 * 256 * 2);
    unsigned short* W1lo = (unsigned short*)alloc((size_t)128 * 256 * 2);
    unsigned short* W2hi = (unsigned short*)alloc((size_t)64 * 128 * 2);
    unsigned short* W2lo = (unsigned short*)alloc((size_t)64 * 128 * 2);
    float* Vf   = (float*)alloc((size_t)32 * 128 * 4);
    unsigned short* Vh = (unsigned short*)alloc((size_t)32 * 128 * 2);
    unsigned short* Vl = (unsigned short*)alloc((size_t)32 * 128 * 2);
    float* cvec = (float*)alloc((size_t)32 * 4);
    float* x1a_all  = (float*)alloc((size_t)10 * N * 4);
    float* xa2a_all = (float*)alloc((size_t)10 * N * 4);
    float* h1aA = (float*)alloc((size_t)N * 4);
    float* h1aB = (float*)alloc((size_t)N * 4);
    int* row_ptr  = (int*)alloc((size_t)(N + 1) * 4);
    int* cnt      = (int*)alloc((size_t)N * 4);
    int* bsums    = (int*)alloc((size_t)1024);
    int* t_sorted = (int*)alloc((size_t)E * 4);

    // CSR build
    hipMemsetAsync(cnt, 0, (size_t)N * 4, stream);
    k_count<<<(E + 255) / 256, 256, 0, stream>>>(s, cnt, E);
    k_scan1<<<G, 256, 0, stream>>>(cnt, bsums, N);
    k_scan2<<<1, 256, 0, stream>>>(bsums, G);
    k_scan3<<<G, 256, 0, stream>>>(cnt, bsums, row_ptr, N);
    hipMemsetAsync(cnt, 0, (size_t)N * 4, stream);
    k_scatter<<<(E + 255) / 256, 256, 0, stream>>>(s, t, row_ptr, cnt, t_sorted, E);

    // W splits + V prep
    k_wsplit<<<(10 * 16384 + 255) / 256, 256, 0, stream>>>(fcsW, Whi, Wlo, 10 * 16384);
    k_wsplit<<<(128 * 256 + 255) / 256, 256, 0, stream>>>(fc1W, W1hi, W1lo, 128 * 256);
    k_wsplit<<<(64 * 128 + 255) / 256, 256, 0, stream>>>(fc2W, W2hi, W2lo, 64 * 128);
    hipMemsetAsync(Vf, 0, (size_t)32 * 128 * 4, stream);
    hipMemsetAsync(Vh, 0, (size_t)32 * 128 * 2, stream);
    hipMemsetAsync(Vl, 0, (size_t)32 * 128 * 2, stream);
    hipMemsetAsync(cvec, 0, (size_t)32 * 4, stream);
    k_prep<<<10, 256, 0, stream>>>(fcsW, fcsb, a1, a2, Vf, Vh, Vl, cvec);

    // fc1 + relu -> split planes (BM=64)
    k_fc1<<<NB64, 256, 0, stream>>>(x_in, W1hi, W1lo, fc1b, xbuf_hi, xbuf_lo, N);

    // x-side scalars for all hops
    k_xdots<<<NB64, 256, 0, stream>>>(xbuf_hi, xbuf_lo, Vh, Vl, cvec,
                                      x1a_all, xa2a_all, N);

    // hops: fused gather + GEMM, ping-pong h / h1a
    const unsigned short* table = xbuf_hi;
    const float* h1in = xa2a_all;  // hop 0: h1 == xa2 (h == x)
    for (int i = 0; i < 10; ++i) {
        unsigned short* hout = (i & 1) ? hB : hA;
        float* h1out = (i & 1) ? h1aB : h1aA;
        const float* vnext = (i < 9) ? (Vf + (size_t)(16 + i + 1) * 128) : nullptr;
        k_hop<<<NB32, 256, 0, stream>>>(table, xbuf_hi,
                                        x1a_all + (size_t)i * N, xa2a_all + (size_t)i * N,
                                        h1in, row_ptr, t_sorted,
                                        Whi + (size_t)i * 16384, Wlo + (size_t)i * 16384,
                                        fcsb + (size_t)i * 128, vnext, cvec + (16 + i + 1),
                                        hout, h1out, N);
        table = hout;
        h1in = h1out;
    }

    // fc2
    k_fc2<<<NB64, 256, 0, stream>>>(table, W2hi, W2lo, fc2b, (float*)d_out, N);
}